// Round 4
// baseline (46.581 us; speedup 1.0000x reference)
//
#include <hip/hip_runtime.h>
#include <math.h>

#define MU 1e-4f
#define COUNT_EPS 1e-4f
#define TWO_PI_F 6.2831853071795864769f

constexpr int P   = 8;    // partitions (reference fixes 8)
constexpr int N   = 128;  // neighbors
constexpr int WPB = 4;    // waves per block (256 threads)
constexpr int RPW = 2;    // rows per wave

// swizzled LDS slot for (neighbor n, 16B-chunk c): conflict-free on both the
// coalesced write side and the per-neighbor read side (verified per 8-lane
// phase group: 8 distinct (bit6, bits[5:4]) combos -> all 32 banks covered).
__device__ __forceinline__ int slot(int n, int c) {
    return (n << 2) | (c ^ ((n >> 1) & 3));
}

__global__ __launch_bounds__(256) void social_circle_kernel(
    const float* __restrict__ trajs,   // [B, 8, 2]
    const float* __restrict__ nei,     // [B, 128, 8, 2]
    float* __restrict__ social,        // [B, P, 3]
    float* __restrict__ fdir,          // [B, N]
    int B)
{
    const int lane = threadIdx.x & 63;
    const int wib  = threadIdx.x >> 6;
    const int wave = blockIdx.x * WPB + wib;

    __shared__ float4 stage_s[WPB][N * 4];   // 8 KB per wave
    __shared__ float  accs[WPB][P * 4];      // {speed,dist,dir,count} x 8
    float4* st  = stage_s[wib];
    float*  acc = accs[wib];

    const size_t b0 = (size_t)wave * RPW;
    if (b0 >= (size_t)B) return;

    // ---- prefetch row 0, fully coalesced: instr k covers 1 KiB contiguous ----
    float4 pf[8];
    {
        const float4* src = (const float4*)(nei + b0 * (N * 16));
        #pragma unroll
        for (int k = 0; k < 8; ++k) pf[k] = src[k * 64 + lane];
    }

    for (int i = 0; i < RPW; ++i) {
        const size_t b = b0 + i;
        if (b >= (size_t)B) break;

        if (lane < P * 4) acc[lane] = 0.0f;

        // stage current row into LDS (swizzled); DS pipe is in-order per wave,
        // so these writes queue behind the previous row's reads.
        #pragma unroll
        for (int k = 0; k < 8; ++k) {
            const int f = k * 64 + lane;         // float4 index within row
            st[slot(f >> 2, f & 3)] = pf[k];
        }

        // prefetch next row (coalesced) while this row is processed
        if (i + 1 < RPW && b + 1 < (size_t)B) {
            const float4* src = (const float4*)(nei + (b + 1) * (N * 16));
            #pragma unroll
            for (int k = 0; k < 8; ++k) pf[k] = src[k * 64 + lane];
        }

        // trajs row: wave-uniform address -> scalar loads
        const float* tb = trajs + b * 16;
        const float fx0 = tb[0],  fy0 = tb[1];   // t=0
        const float lx  = tb[14], ly  = tb[15];  // t=7
        const float ox = lx - fx0, oy = ly - fy0;
        const float obs_len = sqrtf(ox * ox + oy * oy);

        float dval[2], spd[2], dst[2];
        int   idxv[2];
        bool  val[2];

        #pragma unroll
        for (int h = 0; h < 2; ++h) {
            const int n = lane + 64 * h;
            const float4 q0 = st[slot(n, 0)];   // {t0.x,t0.y,t1.x,t1.y}
            const float4 q1 = st[slot(n, 1)];
            const float4 q2 = st[slot(n, 2)];
            const float4 q3 = st[slot(n, 3)];   // {t6.x,t6.y,t7.x,t7.y}

            const float msum = q0.x + q0.y + q0.z + q0.w
                             + q1.x + q1.y + q1.z + q1.w
                             + q2.x + q2.y + q2.z + q2.w
                             + q3.x + q3.y + q3.z + q3.w;

            const float ex = q3.z, ey = q3.w;          // t=7
            const float nvx = ex - q0.x, nvy = ey - q0.y;
            const float nl = sqrtf(nvx * nvx + nvy * nvy);
            spd[h] = (nl + MU) / (obs_len + MU);

            const float px = ex - lx, py = ey - ly;
            dst[h] = sqrtf(px * px + py * py);

            float d = atan2f(py, px);
            if (d < 0.0f) d += TWO_PI_F;   // == jnp.mod(atan2, 2pi) on [-pi,pi]
            dval[h] = d;

            idxv[h] = (int)(d / (TWO_PI_F / P));
            // idx==P (d rounded up to 2pi) matches one_hot out-of-range: excluded
            val[h] = (msum != 0.0f) && (idxv[h] >= 0) && (idxv[h] < P);
        }

        #pragma unroll
        for (int h = 0; h < 2; ++h) {
            if (val[h]) {
                float* ap = &acc[idxv[h] * 4];
                atomicAdd(ap + 0, spd[h]);
                atomicAdd(ap + 1, dst[h]);
                atomicAdd(ap + 2, dval[h]);
                atomicAdd(ap + 3, 1.0f);
            }
        }

        // coalesced fdir stores (two contiguous 256B wave stores)
        fdir[b * N + lane]      = dval[0];
        fdir[b * N + 64 + lane] = dval[1];

        // drain this wave's ds_adds before reading buckets (no barrier needed)
        asm volatile("s_waitcnt lgkmcnt(0)" ::: "memory");

        if (lane < P * 3) {
            const int p = lane / 3, f = lane % 3;
            social[b * (P * 3) + lane] = acc[p * 4 + f] / (acc[p * 4 + 3] + COUNT_EPS);
        }
    }
}

extern "C" void kernel_launch(void* const* d_in, const int* in_sizes, int n_in,
                              void* d_out, int out_size, void* d_ws, size_t ws_size,
                              hipStream_t stream) {
    const float* trajs = (const float*)d_in[0];
    const float* nei   = (const float*)d_in[1];
    const int B = in_sizes[0] / 16;  // trajs is [B, 8, 2]

    float* social = (float*)d_out;                       // [B, 8, 3]
    float* fdir   = (float*)d_out + (size_t)B * P * 3;   // [B, 128]

    const int waves  = (B + RPW - 1) / RPW;
    const int blocks = (waves + WPB - 1) / WPB;
    social_circle_kernel<<<blocks, WPB * 64, 0, stream>>>(trajs, nei, social, fdir, B);
}

// Round 6
// 40.827 us; speedup vs baseline: 1.1409x; 1.1409x over previous
//
#include <hip/hip_runtime.h>
#include <math.h>

#define MU 1e-4f
#define COUNT_EPS 1e-4f
#define TWO_PI_F 6.2831853071795864769f

constexpr int P   = 8;    // partitions (reference fixes 8)
constexpr int N   = 128;  // neighbors
constexpr int WPB = 4;    // waves per block (256 threads)
constexpr int RPW = 2;    // rows per wave

// quad-perm ds_swizzle patterns (offset bit15=1, [7:0] = lane selectors)
#define QUAD_BCAST0 0x8000  // (0,0,0,0): broadcast quad lane 0
#define QUAD_BCAST3 0x80FF  // (3,3,3,3): broadcast quad lane 3
#define QUAD_XOR1   0x80B1  // (1,0,3,2): swap within pairs
#define QUAD_XOR2   0x804E  // (2,3,0,1): swap pairs

template <int PAT>
__device__ __forceinline__ float qswz(float v) {
    return __int_as_float(__builtin_amdgcn_ds_swizzle(__float_as_int(v), PAT));
}

__device__ __forceinline__ void process_row(
    size_t b, const float4* pf, const float* __restrict__ trajs,
    float* __restrict__ social, float* __restrict__ fdir,
    float* acc, int lane, int grp, int c)
{
    if (lane < P * 4) acc[lane] = 0.0f;   // per-wave DS order: before atomics

    // trajs row: wave-uniform address -> scalar loads
    const float* tb = trajs + b * 16;
    const float fx0 = tb[0],  fy0 = tb[1];   // t=0
    const float lx  = tb[14], ly  = tb[15];  // t=7
    const float ox = lx - fx0, oy = ly - fy0;
    const float obs_len = sqrtf(ox * ox + oy * oy);

    #pragma unroll
    for (int k = 0; k < 8; ++k) {
        const float4 q = pf[k];   // chunk c of neighbor n = 16k + grp

        // mask sum over all 16 floats of the neighbor: quad tree-reduce
        float s = (q.x + q.y) + (q.z + q.w);
        s += qswz<QUAD_XOR1>(s);
        s += qswz<QUAD_XOR2>(s);

        // first point (chunk0 = {t0.x,t0.y,t1.x,t1.y}) from quad lane 0,
        // last point  (chunk3 = {t6.x,t6.y,t7.x,t7.y}) from quad lane 3
        const float fx = qswz<QUAD_BCAST0>(q.x);
        const float fy = qswz<QUAD_BCAST0>(q.y);
        const float ex = qswz<QUAD_BCAST3>(q.z);
        const float ey = qswz<QUAD_BCAST3>(q.w);

        const float nvx = ex - fx, nvy = ey - fy;
        const float spd = (sqrtf(nvx * nvx + nvy * nvy) + MU) / (obs_len + MU);

        const float px = ex - lx, py = ey - ly;
        const float dst = sqrtf(px * px + py * py);

        float d = atan2f(py, px);
        if (d < 0.0f) d += TWO_PI_F;   // == jnp.mod(atan2, 2pi) on [-pi,pi]

        const int idx = (int)(d / (TWO_PI_F / P));
        // idx==P (d rounded up to 2pi) matches one_hot out-of-range: excluded
        const bool valid = (s != 0.0f) && (idx >= 0) && (idx < P);

        if (c == 0 && valid) {
            float* ap = &acc[idx * 4];
            atomicAdd(ap + 0, spd);
            atomicAdd(ap + 1, dst);
            atomicAdd(ap + 2, d);
            atomicAdd(ap + 3, 1.0f);
        }
        if (c == 3) fdir[b * N + k * 16 + grp] = d;
    }

    // drain this wave's ds atomics before reading buckets (no barrier needed)
    asm volatile("s_waitcnt lgkmcnt(0)" ::: "memory");

    if (lane < P * 3) {
        const int p = lane / 3, f = lane % 3;
        social[b * (P * 3) + lane] = acc[p * 4 + f] / (acc[p * 4 + 3] + COUNT_EPS);
    }
}

__global__ __launch_bounds__(256) void social_circle_kernel(
    const float* __restrict__ trajs,   // [B, 8, 2]
    const float* __restrict__ nei,     // [B, 128, 8, 2]
    float* __restrict__ social,        // [B, P, 3]
    float* __restrict__ fdir,          // [B, N]
    int B)
{
    const int lane = threadIdx.x & 63;
    const int wib  = threadIdx.x >> 6;
    const int wave = blockIdx.x * WPB + wib;
    const int grp  = lane >> 2;   // quad id (0..15)
    const int c    = lane & 3;    // chunk id within quad

    __shared__ float accs[WPB][P * 4];   // {speed,dist,dir,count} x 8, per wave
    float* acc = accs[wib];

    const size_t b0 = (size_t)wave * RPW;
    if (b0 >= (size_t)B) return;

    // row 0: fully coalesced — instr k covers floats [k*256, k*256+256)
    float4 r0[8];
    {
        const float4* src = (const float4*)(nei + b0 * (N * 16));
        #pragma unroll
        for (int k = 0; k < 8; ++k) r0[k] = src[k * 64 + lane];
    }

    // prefetch row 1 before processing row 0 (loads fly under compute)
    const bool has1 = (b0 + 1 < (size_t)B);
    float4 r1[8];
    if (has1) {
        const float4* src = (const float4*)(nei + (b0 + 1) * (N * 16));
        #pragma unroll
        for (int k = 0; k < 8; ++k) r1[k] = src[k * 64 + lane];
    }

    process_row(b0, r0, trajs, social, fdir, acc, lane, grp, c);
    if (has1) process_row(b0 + 1, r1, trajs, social, fdir, acc, lane, grp, c);
}

extern "C" void kernel_launch(void* const* d_in, const int* in_sizes, int n_in,
                              void* d_out, int out_size, void* d_ws, size_t ws_size,
                              hipStream_t stream) {
    const float* trajs = (const float*)d_in[0];
    const float* nei   = (const float*)d_in[1];
    const int B = in_sizes[0] / 16;  // trajs is [B, 8, 2]

    float* social = (float*)d_out;                       // [B, 8, 3]
    float* fdir   = (float*)d_out + (size_t)B * P * 3;   // [B, 128]

    const int waves  = (B + RPW - 1) / RPW;
    const int blocks = (waves + WPB - 1) / WPB;
    social_circle_kernel<<<blocks, WPB * 64, 0, stream>>>(trajs, nei, social, fdir, B);
}

// Round 7
// 17.746 us; speedup vs baseline: 2.6248x; 2.3006x over previous
//
#include <hip/hip_runtime.h>
#include <math.h>

#define MU 1e-4f
#define COUNT_EPS 1e-4f
#define TWO_PI_F 6.28318530717958647692f
#define PI_F 3.14159265358979323846f
#define HALF_PI_F 1.57079632679489661923f

constexpr int P   = 8;    // partitions (reference fixes 8)
constexpr int N   = 128;  // neighbors
constexpr int WPB = 4;    // waves per block

// ---- DPP wave-64 sum: result valid in lane 63 (rocPRIM idiom) ----
template <int CTRL>
__device__ __forceinline__ float dpp_add(float v) {
    int m = __builtin_amdgcn_update_dpp(0, __float_as_int(v), CTRL, 0xF, 0xF, true);
    return v + __int_as_float(m);
}
__device__ __forceinline__ float wave_sum(float v) {
    v = dpp_add<0x111>(v);   // row_shr:1
    v = dpp_add<0x112>(v);   // row_shr:2
    v = dpp_add<0x114>(v);   // row_shr:4
    v = dpp_add<0x118>(v);   // row_shr:8  -> lane15/31/47/63 hold row sums
    v = dpp_add<0x142>(v);   // row_bcast:15 (invalid src -> 0)
    v = dpp_add<0x143>(v);   // row_bcast:31
    return v;                // lane 63 = full 64-lane sum
}

// branchless atan2 in [0, 2*pi): poly A&S 4.4.49, |err| <= 1e-5 rad
__device__ __forceinline__ float atan2_2pi(float y, float x) {
    const float ax = fabsf(x), ay = fabsf(y);
    const float mx = fmaxf(ax, ay), mn = fminf(ax, ay);
    const float t  = mn * __builtin_amdgcn_rcpf(fmaxf(mx, 1e-30f)); // (0,0) -> 0
    const float t2 = t * t;
    float a = fmaf(t2, 0.0208351f, -0.0851330f);
    a = fmaf(t2, a, 0.1801410f);
    a = fmaf(t2, a, -0.3302995f);
    a = fmaf(t2, a, 0.9998660f);
    a *= t;                                   // atan(mn/mx) in [0, pi/4]
    a = (ay > ax) ? (HALF_PI_F - a) : a;      // [0, pi/2]
    a = (x < 0.0f) ? (PI_F - a) : a;          // [0, pi]
    return (y < 0.0f) ? (TWO_PI_F - a) : a;   // [0, 2*pi)
}

struct Feat { float spd, dst, dir; int idx; };

__device__ __forceinline__ Feat features(const float4* c, float robs,
                                          float lx, float ly, float inv_step) {
    Feat f;
    const float4 v0 = c[0], v1 = c[1], v2 = c[2], v3 = c[3];
    const float msum = ((v0.x + v0.y) + (v0.z + v0.w))
                     + ((v1.x + v1.y) + (v1.z + v1.w))
                     + ((v2.x + v2.y) + (v2.z + v2.w))
                     + ((v3.x + v3.y) + (v3.z + v3.w));
    const float ex = v3.z, ey = v3.w;                 // t=7
    const float nvx = ex - v0.x, nvy = ey - v0.y;     // t7 - t0
    f.spd = (__builtin_amdgcn_sqrtf(fmaf(nvx, nvx, nvy * nvy)) + MU) * robs;
    const float px = ex - lx, py = ey - ly;
    f.dst = __builtin_amdgcn_sqrtf(fmaf(px, px, py * py));
    f.dir = atan2_2pi(py, px);
    const int idx = (int)(f.dir * inv_step);
    // msum==0 -> invalid; idx==P (dir rounded to 2*pi) matches one_hot OOR: excluded
    f.idx = ((msum != 0.0f) && (idx < P)) ? idx : -1;
    return f;
}

__global__ __launch_bounds__(256) void social_circle_kernel(
    const float* __restrict__ trajs,   // [B, 8, 2]
    const float* __restrict__ nei,     // [B, 128, 8, 2]
    float* __restrict__ social,        // [B, P, 3]
    float* __restrict__ fdir,          // [B, N]
    int B)
{
    const int lane = threadIdx.x & 63;
    const int wib  = threadIdx.x >> 6;
    const size_t b = (size_t)blockIdx.x * WPB + wib;   // one row per wave
    if (b >= (size_t)B) return;

    const float inv_step = 1.0f / (TWO_PI_F / (float)P);

    // 8x dwordx4 in flight; lane handles neighbors n0=lane, n1=lane+64
    const float4* base = (const float4*)(nei + b * (N * 16));
    float4 c0[4], c1[4];
    #pragma unroll
    for (int k = 0; k < 4; ++k) c0[k] = base[lane * 4 + k];
    #pragma unroll
    for (int k = 0; k < 4; ++k) c1[k] = base[(lane + 64) * 4 + k];

    // trajs row: wave-uniform -> scalar loads
    const float* tb = trajs + b * 16;
    const float lx = tb[14], ly = tb[15];
    const float ox = lx - tb[0], oy = ly - tb[1];
    const float robs = __builtin_amdgcn_rcpf(
        __builtin_amdgcn_sqrtf(fmaf(ox, ox, oy * oy)) + MU);

    const Feat f0 = features(c0, robs, lx, ly, inv_step);
    const Feat f1 = features(c1, robs, lx, ly, inv_step);

    // coalesced f_direction stores (two contiguous 256B wave stores)
    fdir[b * N + lane]      = f0.dir;
    fdir[b * N + 64 + lane] = f1.dir;

    // per-bucket sums on the VALU pipe (DPP) + scalar counts (ballot/popc).
    // No LDS, no DS atomics, no barriers.
    float4 o[6];   // 24 outputs [p][f]; only lane 63's values are meaningful
    #pragma unroll
    for (int p = 0; p < P; ++p) {
        const bool m0 = (f0.idx == p);
        const bool m1 = (f1.idx == p);
        const int cnt = __popcll(__ballot(m0)) + __popcll(__ballot(m1));
        const float rc = __builtin_amdgcn_rcpf((float)cnt + COUNT_EPS);
        const float s_spd = wave_sum((m0 ? f0.spd : 0.0f) + (m1 ? f1.spd : 0.0f));
        const float s_dst = wave_sum((m0 ? f0.dst : 0.0f) + (m1 ? f1.dst : 0.0f));
        const float s_dir = wave_sum((m0 ? f0.dir : 0.0f) + (m1 ? f1.dir : 0.0f));
        const int k = p * 3;
        ((float*)o)[k + 0] = s_spd * rc;
        ((float*)o)[k + 1] = s_dst * rc;
        ((float*)o)[k + 2] = s_dir * rc;
    }

    if (lane == 63) {
        float4* sp = (float4*)(social + b * (P * 3));   // 96B, 16B-aligned
        #pragma unroll
        for (int j = 0; j < 6; ++j) sp[j] = o[j];
    }
}

extern "C" void kernel_launch(void* const* d_in, const int* in_sizes, int n_in,
                              void* d_out, int out_size, void* d_ws, size_t ws_size,
                              hipStream_t stream) {
    const float* trajs = (const float*)d_in[0];
    const float* nei   = (const float*)d_in[1];
    const int B = in_sizes[0] / 16;  // trajs is [B, 8, 2]

    float* social = (float*)d_out;                       // [B, 8, 3]
    float* fdir   = (float*)d_out + (size_t)B * P * 3;   // [B, 128]

    const int blocks = (B + WPB - 1) / WPB;
    social_circle_kernel<<<blocks, WPB * 64, 0, stream>>>(trajs, nei, social, fdir, B);
}